// Round 9
// baseline (929.461 us; speedup 1.0000x reference)
//
#include <hip/hip_runtime.h>
#include <hip/hip_fp16.h>
#include <math.h>

#define SEQ 343
#define CCH 192
#define NWIN 128
#define NHEAD 6
#define TOK (NWIN * SEQ)  // 43904

typedef __bf16 bf16x8 __attribute__((ext_vector_type(8)));
typedef float f32x4 __attribute__((ext_vector_type(4)));
typedef float f32x16 __attribute__((ext_vector_type(16)));
typedef unsigned short ushort8 __attribute__((ext_vector_type(8)));
typedef _Float16 half8 __attribute__((ext_vector_type(8)));
typedef _Float16 half4 __attribute__((ext_vector_type(4)));

__device__ __forceinline__ unsigned short f2bf(float f) {
    unsigned u = __float_as_uint(f);
    u += 0x7FFF + ((u >> 16) & 1);
    return (unsigned short)(u >> 16);
}

// tanh-approx gelu (matches jax.nn.gelu approximate=True), via fast exp
__device__ __forceinline__ float gelu_tanh(float x) {
    const float k0 = 0.7978845608028654f;
    const float k1 = 0.044715f;
    float y = k0 * (x + k1 * x * x * x);
    float t = 1.0f - 2.0f / (__expf(2.0f * y) + 1.0f);
    return 0.5f * x * (1.0f + t);
}

// async global->LDS, 16B per lane
__device__ __forceinline__ void gld16(void* l, const void* g) {
    __builtin_amdgcn_global_load_lds((const __attribute__((address_space(1))) unsigned int*)g,
                                     (__attribute__((address_space(3))) unsigned int*)l, 16, 0, 0);
}

// ---------------- shift (+3 src) + window partition: x(28,56,28,192) -> xw(128,343,192) fp32
__global__ __launch_bounds__(256) void k_shift_part(const float* __restrict__ x,
                                                    float* __restrict__ xw) {
    int idx = blockIdx.x * 256 + threadIdx.x;  // float4 index
    if (idx >= TOK * 48) return;
    int c4 = idx % 48;
    int tok = idx / 48;
    int t = tok % SEQ;
    int wn = tok / SEQ;
    int tw = t % 7, th = (t / 7) % 7, td = t / 49;
    int ww = wn & 3, wh = (wn >> 2) & 7, wd = wn >> 5;
    int sd = (wd * 7 + td + 3) % 28;
    int sh = (wh * 7 + th + 3) % 56;
    int sw = (ww * 7 + tw + 3) % 28;
    const float4* src = (const float4*)(x + (size_t)((sd * 56 + sh) * 28 + sw) * CCH);
    ((float4*)xw)[idx] = src[c4];
}

// ---------------- LayerNorm fp32 -> bf16 (GEMM A operand)
__global__ __launch_bounds__(256) void k_ln_bf(const float* __restrict__ in,
                                               const float* __restrict__ w,
                                               const float* __restrict__ b,
                                               unsigned short* __restrict__ out, int rows) {
    int row = blockIdx.x * 4 + (threadIdx.x >> 6);
    int lane = threadIdx.x & 63;
    if (row >= rows) return;
    const float* p = in + (size_t)row * CCH;
    float v0 = p[lane], v1 = p[lane + 64], v2 = p[lane + 128];
    float s = v0 + v1 + v2;
#pragma unroll
    for (int off = 32; off > 0; off >>= 1) s += __shfl_xor(s, off);
    float mu = s * (1.0f / 192.0f);
    float d0 = v0 - mu, d1 = v1 - mu, d2 = v2 - mu;
    float vv = d0 * d0 + d1 * d1 + d2 * d2;
#pragma unroll
    for (int off = 32; off > 0; off >>= 1) vv += __shfl_xor(vv, off);
    float rs = rsqrtf(vv * (1.0f / 192.0f) + 1e-5f);
    unsigned short* q = out + (size_t)row * CCH;
    q[lane] = f2bf(d0 * rs * w[lane] + b[lane]);
    q[lane + 64] = f2bf(d1 * rs * w[lane + 64] + b[lane + 64]);
    q[lane + 128] = f2bf(d2 * rs * w[lane + 128] + b[lane + 128]);
}

// ---------------- final LN + window reverse + roll(+3) -> d_out (fp32)
__global__ __launch_bounds__(256) void k_ln_out(const float* __restrict__ xw,
                                                const float* __restrict__ w,
                                                const float* __restrict__ b,
                                                float* __restrict__ out) {
    int row = blockIdx.x * 4 + (threadIdx.x >> 6);
    int lane = threadIdx.x & 63;
    if (row >= TOK) return;
    int d = row / 1568;
    int hh = (row / 28) % 56;
    int wv = row % 28;
    int sd = (d + 25) % 28, sh = (hh + 53) % 56, sw = (wv + 25) % 28;
    int wn = (sd / 7) * 32 + (sh / 7) * 4 + (sw / 7);
    int t = (sd % 7) * 49 + (sh % 7) * 7 + (sw % 7);
    const float* p = xw + ((size_t)wn * SEQ + t) * CCH;
    float v0 = p[lane], v1 = p[lane + 64], v2 = p[lane + 128];
    float s = v0 + v1 + v2;
#pragma unroll
    for (int off = 32; off > 0; off >>= 1) s += __shfl_xor(s, off);
    float mu = s * (1.0f / 192.0f);
    float d0 = v0 - mu, d1 = v1 - mu, d2 = v2 - mu;
    float vv = d0 * d0 + d1 * d1 + d2 * d2;
#pragma unroll
    for (int off = 32; off > 0; off >>= 1) vv += __shfl_xor(vv, off);
    float rs = rsqrtf(vv * (1.0f / 192.0f) + 1e-5f);
    float* q = out + (size_t)row * CCH;
    q[lane] = d0 * rs * w[lane] + b[lane];
    q[lane + 64] = d1 * rs * w[lane + 64] + b[lane + 64];
    q[lane + 128] = d2 * rs * w[lane + 128] + b[lane + 128];
}

// ---------------- weight prep: fp32 [K][N] -> bf16 transposed [N][K], both layers
__global__ __launch_bounds__(256) void k_wprep(const float* __restrict__ qkv_w,
                                               const float* __restrict__ out_w,
                                               const float* __restrict__ ff1_w,
                                               const float* __restrict__ ff2_w,
                                               unsigned short* __restrict__ wt) {
    int idx = blockIdx.x * 256 + threadIdx.x;
    if (idx >= 1179648) return;
    int l = idx / 589824;
    int r = idx - l * 589824;
    const float* src;
    int Kd, Nd, off;
    if (r < 110592)      { src = qkv_w + (size_t)l * 110592; Kd = 192; Nd = 576;  off = r; }
    else if (r < 147456) { src = out_w + (size_t)l * 36864;  Kd = 192; Nd = 192;  off = r - 110592; }
    else if (r < 442368) { src = ff1_w + (size_t)l * 294912; Kd = 192; Nd = 1536; off = r - 147456; }
    else                 { src = ff2_w + (size_t)l * 147456; Kd = 768; Nd = 192;  off = r - 442368; }
    int n = off / Kd, k = off - n * Kd;
    wt[idx] = f2bf(src[(size_t)k * Nd + n]);
}

// ---------------- combined mask+bias (log2 domain): cb[cl][h][kp][q], f16 pair for k=2kp,2kp+1
__global__ void k_cbgen2(const float* __restrict__ mask, const float* __restrict__ rpb,
                         unsigned* __restrict__ cb) {
    int q = threadIdx.x;   // 0..351
    int kp = blockIdx.x;   // 0..175
    int h = blockIdx.y;    // 0..5
    int cl = blockIdx.z;   // 0..7
    int wn = ((cl & 4) ? 96 : 0) + ((cl & 2) ? 28 : 0) + ((cl & 1) ? 3 : 0);
    const float LOG2E = 1.4426950408889634f;
    int qd = q / 49, qh = (q / 7) % 7, qw = q % 7;
    unsigned short v[2];
#pragma unroll
    for (int t = 0; t < 2; ++t) {
        int k = 2 * kp + t;
        float val = -14000.0f;
        if (k < SEQ && q < SEQ) {
            float mk = mask[((size_t)wn * SEQ + k) * SEQ + q];  // mask symmetric in !=0
            if (mk == 0.0f) {
                int kd = k / 49, kh = (k / 7) % 7, kw = k % 7;
                int rel = (qd - kd + 6) * 169 + (qh - kh + 6) * 13 + (qw - kw + 6);
                val = rpb[(size_t)rel * NHEAD + h] * LOG2E;
            }
        }
        v[t] = __half_as_ushort(__float2half_rn(val));
    }
    cb[((size_t)(cl * NHEAD + h) * 176 + kp) * 352 + q] = (unsigned)v[0] | ((unsigned)v[1] << 16);
}

// ---------------- 32x32x16 MFMA GEMM with T14 async reg-prefetch K-pipeline.
// Tile 0 via global_load_lds DMA; tiles 1+ reg-staged during previous tile's MFMAs.
// BM=128, BK=64 (rows = 128B), XOR-swizzle (pre-swizzled global source, linear LDS).
// MODE 0 (qkv): BN=192 -> Q(scaled)/K -> outH[row][384]; V -> outV transposed.
// MODE 1: BN=64, outF += acc + bias (residual fp32)
// MODE 2 (GLU): BN=64, Wt rows [n0,n0+64)=u, [768+n0,...)=g; outB = bf16(u * gelu(g))
template <int MODE>
__global__ __launch_bounds__(256) void k_gemm32(const unsigned short* __restrict__ A,
                                                const unsigned short* __restrict__ Wt,
                                                const float* __restrict__ bias,
                                                float* __restrict__ outF,
                                                unsigned short* __restrict__ outB,
                                                _Float16* __restrict__ outH,
                                                _Float16* __restrict__ outV,
                                                int N, int K) {
    constexpr int BN = (MODE == 0) ? 192 : 64;
    constexpr int NF = (MODE == 0) ? 3 : 1;          // n-frags (of 32) per wave
    constexpr int WNC = NF * 32;                     // wave n-extent
    constexpr int BROWS = (MODE == 0) ? 192 : ((MODE == 2) ? 128 : 64);
    constexpr int BCH = (BROWS * 128) / 4096;        // B chunks (4KB each)
    __shared__ char AsB[16384];
    __shared__ char BsB[BROWS * 128];
    const int tid = threadIdx.x;
    const int n0 = blockIdx.x * BN;
    const size_t m0 = (size_t)blockIdx.y * 128;
    const int lane = tid & 63, wid = tid >> 6;
    const int wm = wid >> 1, wn = wid & 1;
    const int ln31 = lane & 31, hi16 = (lane >> 5) * 16;
    const int xorv = (ln31 & 7) << 4;
    const size_t ldb = (size_t)K * 2;  // row pitch (bytes) of both A and Wt

    f32x16 acc[2][NF];
    f32x16 accG[2];
#pragma unroll
    for (int mi = 0; mi < 2; ++mi) {
#pragma unroll
        for (int nj = 0; nj < NF; ++nj) acc[mi][nj] = (f32x16)(0.f);
        accG[mi] = (f32x16)(0.f);
    }

    // ---- prologue: DMA-stage tile 0
#pragma unroll
    for (int i = 0; i < 4; ++i) {
        int s = i * 4096 + tid * 16;
        int r = s >> 7;
        int cbx = (s & 127) ^ ((r & 7) << 4);
        gld16(AsB + s, (const char*)A + (m0 + r) * ldb + cbx);
    }
#pragma unroll
    for (int i = 0; i < BCH; ++i) {
        int s = i * 4096 + tid * 16;
        int r = s >> 7;
        int cbx = (s & 127) ^ ((r & 7) << 4);
        int grow = n0 + r + ((MODE == 2 && r >= 64) ? 704 : 0);
        gld16(BsB + s, (const char*)Wt + (size_t)grow * ldb + cbx);
    }
    __syncthreads();

    for (int kb = 0; kb < K; kb += 64) {
        const bool more = (kb + 64) < K;
        uint4 ra[4], rb[BCH];
        if (more) {
            const size_t ko = (size_t)(kb + 64) * 2;
#pragma unroll
            for (int i = 0; i < 4; ++i) {
                int s = i * 4096 + tid * 16;
                int r = s >> 7;
                int cbx = (s & 127) ^ ((r & 7) << 4);
                ra[i] = *(const uint4*)((const char*)A + (m0 + r) * ldb + ko + cbx);
            }
#pragma unroll
            for (int i = 0; i < BCH; ++i) {
                int s = i * 4096 + tid * 16;
                int r = s >> 7;
                int cbx = (s & 127) ^ ((r & 7) << 4);
                int grow = n0 + r + ((MODE == 2 && r >= 64) ? 704 : 0);
                rb[i] = *(const uint4*)((const char*)Wt + (size_t)grow * ldb + ko + cbx);
            }
        }
        // ---- compute current tile: 4 k-steps of 16
#pragma unroll
        for (int ks = 0; ks < 4; ++ks) {
            const int ccb = (ks * 32 + hi16) ^ xorv;
            bf16x8 a0 = *(const bf16x8*)(AsB + (wm * 64 + ln31) * 128 + ccb);
            bf16x8 a1 = *(const bf16x8*)(AsB + (wm * 64 + 32 + ln31) * 128 + ccb);
            if (MODE == 2) {
                bf16x8 bu = *(const bf16x8*)(BsB + (wn * 32 + ln31) * 128 + ccb);
                bf16x8 bg = *(const bf16x8*)(BsB + (64 + wn * 32 + ln31) * 128 + ccb);
                acc[0][0] = __builtin_amdgcn_mfma_f32_32x32x16_bf16(a0, bu, acc[0][0], 0, 0, 0);
                acc[1][0] = __builtin_amdgcn_mfma_f32_32x32x16_bf16(a1, bu, acc[1][0], 0, 0, 0);
                accG[0] = __builtin_amdgcn_mfma_f32_32x32x16_bf16(a0, bg, accG[0], 0, 0, 0);
                accG[1] = __builtin_amdgcn_mfma_f32_32x32x16_bf16(a1, bg, accG[1], 0, 0, 0);
            } else {
#pragma unroll
                for (int nj = 0; nj < NF; ++nj) {
                    bf16x8 b = *(const bf16x8*)(BsB + (wn * WNC + nj * 32 + ln31) * 128 + ccb);
                    acc[0][nj] = __builtin_amdgcn_mfma_f32_32x32x16_bf16(a0, b, acc[0][nj], 0, 0, 0);
                    acc[1][nj] = __builtin_amdgcn_mfma_f32_32x32x16_bf16(a1, b, acc[1][nj], 0, 0, 0);
                }
            }
        }
        if (more) {
            __syncthreads();  // all waves done reading LDS
#pragma unroll
            for (int i = 0; i < 4; ++i) *(uint4*)(AsB + i * 4096 + tid * 16) = ra[i];
#pragma unroll
            for (int i = 0; i < BCH; ++i) *(uint4*)(BsB + i * 4096 + tid * 16) = rb[i];
            __syncthreads();  // writes visible
        }
    }

    // ---- epilogue. C/D: col=lane&31, row=(reg&3)+8*(reg>>2)+4*(lane>>5)
    const float S2LOG = 0.17677669529663687f * 1.4426950408889634f;  // scale*log2e
    const int rbase = (int)m0 + wm * 64 + ((lane >> 5) << 2);
    const int cbase = n0 + wn * WNC + ln31;
#pragma unroll
    for (int mi = 0; mi < 2; ++mi) {
#pragma unroll
        for (int nj = 0; nj < NF; ++nj) {
            const int gc = cbase + nj * 32;
            const float bb = bias[gc];
            const float bgv = (MODE == 2) ? bias[768 + gc] : 0.f;
#pragma unroll
            for (int reg = 0; reg < 16; ++reg) {
                const int row = rbase + mi * 32 + (reg & 3) + ((reg >> 2) << 3);
                float v = acc[mi][nj][reg] + bb;
                if (MODE == 1) {
                    outF[(size_t)row * N + gc] += v;
                } else if (MODE == 0) {
                    if (n0 < 384) {
                        outH[(size_t)row * 384 + gc] = (_Float16)(n0 == 0 ? v * S2LOG : v);
                    } else {
                        int d = gc - 384, hh = d >> 5, dd = d & 31;
                        int wnn = row / 343, qq = row - wnn * 343;
                        outV[(((size_t)wnn * NHEAD + hh) * 32 + dd) * 344 + qq] = (_Float16)v;
                    }
                } else {
                    float g = accG[mi][reg] + bgv;
                    outB[(size_t)row * 768 + gc] = f2bf(v * gelu_tanh(g));
                }
            }
        }
    }
}

// ---------------- MFMA attention (attn3, measured 74us): block per (head, window), 4 waves.
// S^T = mfma(K, Q^T) so softmax row is lane-local over k; PV via per-wave LDS P buffer.
__global__ __launch_bounds__(256) void k_attn3(const _Float16* __restrict__ qk,  // [TOK][384]
                                               const _Float16* __restrict__ vt,  // [128][6][32][344]
                                               const unsigned* __restrict__ cb,
                                               unsigned short* __restrict__ o) {
    __shared__ _Float16 Ks[352][40];       // 28160 B, pad 40 -> A-frag reads conflict-free
    __shared__ _Float16 Vt[32][360];       // 23040 B (pad 360)
    __shared__ _Float16 Pb[4][48][16][4];  // 24576 B, per-wave P buffer [k/4][q][4]
    const int h = blockIdx.x;
    const int wn = blockIdx.y;
    const int tid = threadIdx.x;
    const _Float16* kbase = qk + (size_t)wn * SEQ * 384 + 192 + h * 32;
    for (int j = tid; j < 352 * 4; j += 256) {
        int s = j >> 2, c = (j & 3) * 8;
        half8 v = {};
        if (s < SEQ) v = *(const half8*)&kbase[(size_t)s * 384 + c];
        *(half8*)&Ks[s][c] = v;
    }
    const _Float16* vbase = vt + ((size_t)wn * NHEAD + h) * 32 * 344;
    for (int j = tid; j < 32 * 44; j += 256) {
        int d = j / 44, c = (j % 44) * 8;
        half8 v = {};
        if (c + 7 <= 342) {
            v = *(const half8*)&vbase[(size_t)d * 344 + c];
        } else if (c <= 342) {
#pragma unroll
            for (int i = 0; i < 8; ++i) v[i] = (c + i <= 342) ? vbase[(size_t)d * 344 + c + i] : (_Float16)0.f;
        }
        *(half8*)&Vt[d][c] = v;
    }
    __syncthreads();
    const int wid = tid >> 6, lane = tid & 63;
    const int qloc = lane & 15, g = lane >> 4;
    int cls = (((wn >> 5) == 3) ? 4 : 0) | ((((wn >> 2) & 7) == 7) ? 2 : 0) | (((wn & 3) == 3) ? 1 : 0);
    const unsigned* cbb = cb + (size_t)(cls * NHEAD + h) * 176 * 352;
    for (int qt = wid; qt < 22; qt += 4) {
        const int q0 = qt * 16;
        const int qrow = q0 + qloc;
        half8 qf = {};
        if (qrow < SEQ) qf = *(const half8*)&qk[((size_t)wn * SEQ + qrow) * 384 + h * 32 + g * 8];
        f32x4 st[22];
#pragma unroll
        for (int kt = 0; kt < 22; ++kt) {
            half8 kf = *(const half8*)&Ks[kt * 16 + qloc][g * 8];
            st[kt] = __builtin_amdgcn_mfma_f32_16x16x32_f16(kf, qf, (f32x4){0.f, 0.f, 0.f, 0.f}, 0, 0, 0);
        }
        float m = -1e30f;
#pragma unroll
        for (int kt = 0; kt < 22; ++kt) {
            const unsigned* cp = cbb + (size_t)(kt * 8 + g * 2) * 352 + q0 + qloc;
            unsigned b0 = cp[0];
            unsigned b1 = cp[352];
            __half2 h0 = *(__half2*)&b0, h1 = *(__half2*)&b1;
            st[kt][0] += __low2float(h0);
            st[kt][1] += __high2float(h0);
            st[kt][2] += __low2float(h1);
            st[kt][3] += __high2float(h1);
            m = fmaxf(m, fmaxf(fmaxf(st[kt][0], st[kt][1]), fmaxf(st[kt][2], st[kt][3])));
        }
        m = fmaxf(m, __shfl_xor(m, 16));
        m = fmaxf(m, __shfl_xor(m, 32));
        float l = 0.f;
        f32x4 acc0 = {0.f, 0.f, 0.f, 0.f}, acc1 = {0.f, 0.f, 0.f, 0.f};
        asm volatile("s_waitcnt lgkmcnt(0)" ::: "memory");
#pragma unroll
        for (int kt = 0; kt < 12; ++kt) {
            float p0 = exp2f(st[kt][0] - m), p1 = exp2f(st[kt][1] - m);
            float p2 = exp2f(st[kt][2] - m), p3 = exp2f(st[kt][3] - m);
            l += (p0 + p1) + (p2 + p3);
            half4 pv = {(_Float16)p0, (_Float16)p1, (_Float16)p2, (_Float16)p3};
            *(half4*)&Pb[wid][kt * 4 + g][qloc][0] = pv;
        }
        asm volatile("s_waitcnt lgkmcnt(0)" ::: "memory");
#pragma unroll
        for (int ks = 0; ks < 6; ++ks) {
            half4 pa = *(half4*)&Pb[wid][ks * 8 + g * 2][qloc][0];
            half4 pb = *(half4*)&Pb[wid][ks * 8 + g * 2 + 1][qloc][0];
            half8 pf = {pa[0], pa[1], pa[2], pa[3], pb[0], pb[1], pb[2], pb[3]};
            half8 v0 = *(const half8*)&Vt[qloc][ks * 32 + g * 8];
            half8 v1 = *(const half8*)&Vt[16 + qloc][ks * 32 + g * 8];
            acc0 = __builtin_amdgcn_mfma_f32_16x16x32_f16(v0, pf, acc0, 0, 0, 0);
            acc1 = __builtin_amdgcn_mfma_f32_16x16x32_f16(v1, pf, acc1, 0, 0, 0);
        }
        asm volatile("s_waitcnt lgkmcnt(0)" ::: "memory");
#pragma unroll
        for (int kt = 12; kt < 22; ++kt) {
            float p0 = exp2f(st[kt][0] - m), p1 = exp2f(st[kt][1] - m);
            float p2 = exp2f(st[kt][2] - m), p3 = exp2f(st[kt][3] - m);
            l += (p0 + p1) + (p2 + p3);
            half4 pv = {(_Float16)p0, (_Float16)p1, (_Float16)p2, (_Float16)p3};
            *(half4*)&Pb[wid][(kt - 12) * 4 + g][qloc][0] = pv;
        }
        asm volatile("s_waitcnt lgkmcnt(0)" ::: "memory");
#pragma unroll
        for (int ks = 0; ks < 5; ++ks) {
            half4 pa = *(half4*)&Pb[wid][ks * 8 + g * 2][qloc][0];
            half4 pb = *(half4*)&Pb[wid][ks * 8 + g * 2 + 1][qloc][0];
            half8 pf = {pa[0], pa[1], pa[2], pa[3], pb[0], pb[1], pb[2], pb[3]};
            half8 v0 = *(const half8*)&Vt[qloc][192 + ks * 32 + g * 8];
            half8 v1 = *(const half8*)&Vt[16 + qloc][192 + ks * 32 + g * 8];
            acc0 = __builtin_amdgcn_mfma_f32_16x16x32_f16(v0, pf, acc0, 0, 0, 0);
            acc1 = __builtin_amdgcn_mfma_f32_16x16x32_f16(v1, pf, acc1, 0, 0, 0);
        }
        l += __shfl_xor(l, 16);
        l += __shfl_xor(l, 32);
        if (qrow < SEQ) {
            float inv = 1.0f / l;
            unsigned short* orow = o + ((size_t)wn * SEQ + qrow) * CCH + h * 32;
            ushort2 w0 = {f2bf(acc0[0] * inv), f2bf(acc0[1] * inv)};
            ushort2 w1 = {f2bf(acc0[2] * inv), f2bf(acc0[3] * inv)};
            ushort2 w2 = {f2bf(acc1[0] * inv), f2bf(acc1[1] * inv)};
            ushort2 w3 = {f2bf(acc1[2] * inv), f2bf(acc1[3] * inv)};
            *(ushort2*)&orow[g * 4] = w0;
            *(ushort2*)&orow[g * 4 + 2] = w1;
            *(ushort2*)&orow[16 + g * 4] = w2;
            *(ushort2*)&orow[16 + g * 4 + 2] = w3;
        }
    }
}

extern "C" void kernel_launch(void* const* d_in, const int* in_sizes, int n_in,
                              void* d_out, int out_size, void* d_ws, size_t ws_size,
                              hipStream_t stream) {
    const float* x     = (const float*)d_in[0];
    const float* mask  = (const float*)d_in[1];
    const float* ln1_w = (const float*)d_in[3];
    const float* ln1_b = (const float*)d_in[4];
    const float* qkv_w = (const float*)d_in[5];
    const float* qkv_b = (const float*)d_in[6];
    const float* out_w = (const float*)d_in[7];
    const float* out_b = (const float*)d_in[8];
    const float* ln2_w = (const float*)d_in[9];
    const float* ln2_b = (const float*)d_in[10];
    const float* ff1_w = (const float*)d_in[11];
    const float* ff1_b = (const float*)d_in[12];
    const float* ff2_w = (const float*)d_in[13];
    const float* ff2_b = (const float*)d_in[14];
    const float* rpb   = (const float*)d_in[15];
    const float* lnf_w = (const float*)d_in[16];
    const float* lnf_b = (const float*)d_in[17];

    char* wsp = (char*)d_ws;
    float* xw = (float*)wsp;                          wsp += (size_t)TOK * 192 * 4;
    unsigned short* hdnb = (unsigned short*)wsp;      wsp += (size_t)TOK * 192 * 2;
    _Float16* qkh = (_Float16*)wsp;                   wsp += (size_t)TOK * 384 * 2;
    _Float16* vth = (_Float16*)wsp;                   wsp += (size_t)NWIN * NHEAD * 32 * 344 * 2;
    unsigned short* glub = (unsigned short*)wsp;      wsp += (size_t)TOK * 768 * 2;
    unsigned short* wt = (unsigned short*)wsp;        wsp += (size_t)1179648 * 2;
    unsigned* cb = (unsigned*)wsp;                    // 48*176*352*4 = 11.9 MB
    float* out = (float*)d_out;

    k_shift_part<<<8232, 256, 0, stream>>>(x, xw);
    k_wprep<<<4608, 256, 0, stream>>>(qkv_w, out_w, ff1_w, ff2_w, wt);
    for (int l = 0; l < 2; ++l) {
        unsigned short* wbase = wt + (size_t)l * 589824;
        k_cbgen2<<<dim3(176, NHEAD, 8), 352, 0, stream>>>(mask, rpb + (size_t)l * 2197 * NHEAD, cb);
        k_ln_bf<<<10976, 256, 0, stream>>>(xw, ln1_w + l * 192, ln1_b + l * 192, hdnb, TOK);
        k_gemm32<0><<<dim3(3, 343), 256, 0, stream>>>(hdnb, wbase, qkv_b + l * 576,
                                                      nullptr, nullptr, qkh, vth, 576, 192);
        k_attn3<<<dim3(NHEAD, NWIN), 256, 0, stream>>>(qkh, vth, cb, hdnb);
        k_gemm32<1><<<dim3(3, 343), 256, 0, stream>>>(hdnb, wbase + 110592, out_b + l * 192,
                                                      xw, nullptr, nullptr, nullptr, 192, 192);
        k_ln_bf<<<10976, 256, 0, stream>>>(xw, ln2_w + l * 192, ln2_b + l * 192, hdnb, TOK);
        k_gemm32<2><<<dim3(12, 343), 256, 0, stream>>>(hdnb, wbase + 147456, ff1_b + l * 1536,
                                                       nullptr, glub, nullptr, nullptr, 768, 192);
        k_gemm32<1><<<dim3(3, 343), 256, 0, stream>>>(glub, wbase + 442368, ff2_b + l * 192,
                                                      xw, nullptr, nullptr, nullptr, 192, 768);
    }
    k_ln_out<<<10976, 256, 0, stream>>>(xw, lnf_w, lnf_b, out);
}

// Round 10
// 674.970 us; speedup vs baseline: 1.3770x; 1.3770x over previous
//
#include <hip/hip_runtime.h>
#include <hip/hip_fp16.h>
#include <math.h>

#define SEQ 343
#define CCH 192
#define NWIN 128
#define NHEAD 6
#define TOK (NWIN * SEQ)  // 43904

typedef __bf16 bf16x8 __attribute__((ext_vector_type(8)));
typedef float f32x4 __attribute__((ext_vector_type(4)));
typedef float f32x16 __attribute__((ext_vector_type(16)));
typedef unsigned short ushort8 __attribute__((ext_vector_type(8)));
typedef _Float16 half8 __attribute__((ext_vector_type(8)));
typedef _Float16 half4 __attribute__((ext_vector_type(4)));

__device__ __forceinline__ unsigned short f2bf(float f) {
    unsigned u = __float_as_uint(f);
    u += 0x7FFF + ((u >> 16) & 1);
    return (unsigned short)(u >> 16);
}

// tanh-approx gelu (matches jax.nn.gelu approximate=True), via fast exp
__device__ __forceinline__ float gelu_tanh(float x) {
    const float k0 = 0.7978845608028654f;
    const float k1 = 0.044715f;
    float y = k0 * (x + k1 * x * x * x);
    float t = 1.0f - 2.0f / (__expf(2.0f * y) + 1.0f);
    return 0.5f * x * (1.0f + t);
}

// async global->LDS, 16B per lane
__device__ __forceinline__ void gld16(void* l, const void* g) {
    __builtin_amdgcn_global_load_lds((const __attribute__((address_space(1))) unsigned int*)g,
                                     (__attribute__((address_space(3))) unsigned int*)l, 16, 0, 0);
}

// ---------------- shift (+3 src) + window partition: x(28,56,28,192) -> xw(128,343,192) fp32
__global__ __launch_bounds__(256) void k_shift_part(const float* __restrict__ x,
                                                    float* __restrict__ xw) {
    int idx = blockIdx.x * 256 + threadIdx.x;  // float4 index
    if (idx >= TOK * 48) return;
    int c4 = idx % 48;
    int tok = idx / 48;
    int t = tok % SEQ;
    int wn = tok / SEQ;
    int tw = t % 7, th = (t / 7) % 7, td = t / 49;
    int ww = wn & 3, wh = (wn >> 2) & 7, wd = wn >> 5;
    int sd = (wd * 7 + td + 3) % 28;
    int sh = (wh * 7 + th + 3) % 56;
    int sw = (ww * 7 + tw + 3) % 28;
    const float4* src = (const float4*)(x + (size_t)((sd * 56 + sh) * 28 + sw) * CCH);
    ((float4*)xw)[idx] = src[c4];
}

// ---------------- LayerNorm fp32 -> bf16 (GEMM A operand)
__global__ __launch_bounds__(256) void k_ln_bf(const float* __restrict__ in,
                                               const float* __restrict__ w,
                                               const float* __restrict__ b,
                                               unsigned short* __restrict__ out, int rows) {
    int row = blockIdx.x * 4 + (threadIdx.x >> 6);
    int lane = threadIdx.x & 63;
    if (row >= rows) return;
    const float* p = in + (size_t)row * CCH;
    float v0 = p[lane], v1 = p[lane + 64], v2 = p[lane + 128];
    float s = v0 + v1 + v2;
#pragma unroll
    for (int off = 32; off > 0; off >>= 1) s += __shfl_xor(s, off);
    float mu = s * (1.0f / 192.0f);
    float d0 = v0 - mu, d1 = v1 - mu, d2 = v2 - mu;
    float vv = d0 * d0 + d1 * d1 + d2 * d2;
#pragma unroll
    for (int off = 32; off > 0; off >>= 1) vv += __shfl_xor(vv, off);
    float rs = rsqrtf(vv * (1.0f / 192.0f) + 1e-5f);
    unsigned short* q = out + (size_t)row * CCH;
    q[lane] = f2bf(d0 * rs * w[lane] + b[lane]);
    q[lane + 64] = f2bf(d1 * rs * w[lane + 64] + b[lane + 64]);
    q[lane + 128] = f2bf(d2 * rs * w[lane + 128] + b[lane + 128]);
}

// ---------------- final LN + window reverse + roll(+3) -> d_out (fp32)
__global__ __launch_bounds__(256) void k_ln_out(const float* __restrict__ xw,
                                                const float* __restrict__ w,
                                                const float* __restrict__ b,
                                                float* __restrict__ out) {
    int row = blockIdx.x * 4 + (threadIdx.x >> 6);
    int lane = threadIdx.x & 63;
    if (row >= TOK) return;
    int d = row / 1568;
    int hh = (row / 28) % 56;
    int wv = row % 28;
    int sd = (d + 25) % 28, sh = (hh + 53) % 56, sw = (wv + 25) % 28;
    int wn = (sd / 7) * 32 + (sh / 7) * 4 + (sw / 7);
    int t = (sd % 7) * 49 + (sh % 7) * 7 + (sw % 7);
    const float* p = xw + ((size_t)wn * SEQ + t) * CCH;
    float v0 = p[lane], v1 = p[lane + 64], v2 = p[lane + 128];
    float s = v0 + v1 + v2;
#pragma unroll
    for (int off = 32; off > 0; off >>= 1) s += __shfl_xor(s, off);
    float mu = s * (1.0f / 192.0f);
    float d0 = v0 - mu, d1 = v1 - mu, d2 = v2 - mu;
    float vv = d0 * d0 + d1 * d1 + d2 * d2;
#pragma unroll
    for (int off = 32; off > 0; off >>= 1) vv += __shfl_xor(vv, off);
    float rs = rsqrtf(vv * (1.0f / 192.0f) + 1e-5f);
    float* q = out + (size_t)row * CCH;
    q[lane] = d0 * rs * w[lane] + b[lane];
    q[lane + 64] = d1 * rs * w[lane + 64] + b[lane + 64];
    q[lane + 128] = d2 * rs * w[lane + 128] + b[lane + 128];
}

// ---------------- weight prep: fp32 [K][N] -> bf16 transposed [N][K], both layers
__global__ __launch_bounds__(256) void k_wprep(const float* __restrict__ qkv_w,
                                               const float* __restrict__ out_w,
                                               const float* __restrict__ ff1_w,
                                               const float* __restrict__ ff2_w,
                                               unsigned short* __restrict__ wt) {
    int idx = blockIdx.x * 256 + threadIdx.x;
    if (idx >= 1179648) return;
    int l = idx / 589824;
    int r = idx - l * 589824;
    const float* src;
    int Kd, Nd, off;
    if (r < 110592)      { src = qkv_w + (size_t)l * 110592; Kd = 192; Nd = 576;  off = r; }
    else if (r < 147456) { src = out_w + (size_t)l * 36864;  Kd = 192; Nd = 192;  off = r - 110592; }
    else if (r < 442368) { src = ff1_w + (size_t)l * 294912; Kd = 192; Nd = 1536; off = r - 147456; }
    else                 { src = ff2_w + (size_t)l * 147456; Kd = 768; Nd = 192;  off = r - 442368; }
    int n = off / Kd, k = off - n * Kd;
    wt[idx] = f2bf(src[(size_t)k * Nd + n]);
}

// ---------------- zero-fill dead rows (343..351) of qT/kT fragment buffers (once)
__global__ void k_zfill(_Float16* __restrict__ qT, _Float16* __restrict__ kT) {
    int wh = blockIdx.x;      // 0..767
    int t = threadIdx.x;      // 0..287
    int qloc = 7 + t / 32;    // 7..15  (qt=21 rows 336+qloc >= 343)
    int c = t % 32;
    int g = c >> 3, c8 = c & 7;
    size_t off = (size_t)wh * 11264 + 21 * 512 + g * 128 + qloc * 8 + c8;
    qT[off] = (_Float16)0.f;
    kT[off] = (_Float16)0.f;
}

// ---------------- combined mask+bias (log2 domain): cb[cl][h][kp][q], f16 pair for k=2kp,2kp+1
__global__ void k_cbgen2(const float* __restrict__ mask, const float* __restrict__ rpb,
                         unsigned* __restrict__ cb) {
    int q = threadIdx.x;   // 0..351
    int kp = blockIdx.x;   // 0..175
    int h = blockIdx.y;    // 0..5
    int cl = blockIdx.z;   // 0..7
    int wn = ((cl & 4) ? 96 : 0) + ((cl & 2) ? 28 : 0) + ((cl & 1) ? 3 : 0);
    const float LOG2E = 1.4426950408889634f;
    int qd = q / 49, qh = (q / 7) % 7, qw = q % 7;
    unsigned short v[2];
#pragma unroll
    for (int t = 0; t < 2; ++t) {
        int k = 2 * kp + t;
        float val = -14000.0f;
        if (k < SEQ && q < SEQ) {
            float mk = mask[((size_t)wn * SEQ + k) * SEQ + q];  // mask symmetric in !=0
            if (mk == 0.0f) {
                int kd = k / 49, kh = (k / 7) % 7, kw = k % 7;
                int rel = (qd - kd + 6) * 169 + (qh - kh + 6) * 13 + (qw - kw + 6);
                val = rpb[(size_t)rel * NHEAD + h] * LOG2E;
            }
        }
        v[t] = __half_as_ushort(__float2half_rn(val));
    }
    cb[((size_t)(cl * NHEAD + h) * 176 + kp) * 352 + q] = (unsigned)v[0] | ((unsigned)v[1] << 16);
}

// ---------------- 32x32x16 MFMA GEMM (round-4 proven structure), global_load_lds staging,
// XOR-swizzle (pre-swizzled global source, linear LDS). BM=128, BK=64.
// MODE 0 (qkv): BN=192 -> Q(scaled)->qT frag layout, K->kT frag layout, V->outV transposed.
// MODE 1: BN=64, outF += acc + bias (residual fp32)
// MODE 2 (GLU): BN=64, Wt rows [n0,n0+64)=u, [768+n0,...)=g; outB = bf16(u * gelu(g))
template <int MODE>
__global__ __launch_bounds__(256) void k_gemm32(const unsigned short* __restrict__ A,
                                                const unsigned short* __restrict__ Wt,
                                                const float* __restrict__ bias,
                                                float* __restrict__ outF,
                                                unsigned short* __restrict__ outB,
                                                _Float16* __restrict__ qT,
                                                _Float16* __restrict__ kT,
                                                _Float16* __restrict__ outV,
                                                int N, int K) {
    constexpr int BN = (MODE == 0) ? 192 : 64;
    constexpr int NF = (MODE == 0) ? 3 : 1;          // n-frags (of 32) per wave
    constexpr int WNC = NF * 32;                     // wave n-extent
    constexpr int BROWS = (MODE == 0) ? 192 : ((MODE == 2) ? 128 : 64);
    constexpr int BCH = (BROWS * 128) / 4096;        // B DMA chunks
    __shared__ char AsB[16384];
    __shared__ char BsB[BROWS * 128];
    const int tid = threadIdx.x;
    const int n0 = blockIdx.x * BN;
    const size_t m0 = (size_t)blockIdx.y * 128;
    const int lane = tid & 63, wid = tid >> 6;
    const int wm = wid >> 1, wn = wid & 1;
    const int ln31 = lane & 31, hi16 = (lane >> 5) * 16;
    const int xorv = (ln31 & 7) << 4;
    const size_t ldb = (size_t)K * 2;  // row pitch (bytes) of both A and Wt

    f32x16 acc[2][NF];
    f32x16 accG[2];
#pragma unroll
    for (int mi = 0; mi < 2; ++mi) {
#pragma unroll
        for (int nj = 0; nj < NF; ++nj) acc[mi][nj] = (f32x16)(0.f);
        accG[mi] = (f32x16)(0.f);
    }

    for (int kb = 0; kb < K; kb += 64) {
        // ---- stage A (16 KB) + B via DMA, global source pre-swizzled
#pragma unroll
        for (int i = 0; i < 4; ++i) {
            int s = i * 4096 + tid * 16;
            int r = s >> 7;
            int cbx = (s & 127) ^ ((r & 7) << 4);
            gld16(AsB + s, (const char*)A + (m0 + r) * ldb + (size_t)kb * 2 + cbx);
        }
#pragma unroll
        for (int i = 0; i < BCH; ++i) {
            int s = i * 4096 + tid * 16;
            int r = s >> 7;
            int cbx = (s & 127) ^ ((r & 7) << 4);
            int grow = n0 + r + ((MODE == 2 && r >= 64) ? 704 : 0);
            gld16(BsB + s, (const char*)Wt + (size_t)grow * ldb + (size_t)kb * 2 + cbx);
        }
        __syncthreads();
        // ---- compute 4 k-steps of 16
#pragma unroll
        for (int ks = 0; ks < 4; ++ks) {
            const int ccb = (ks * 32 + hi16) ^ xorv;
            bf16x8 a0 = *(const bf16x8*)(AsB + (wm * 64 + ln31) * 128 + ccb);
            bf16x8 a1 = *(const bf16x8*)(AsB + (wm * 64 + 32 + ln31) * 128 + ccb);
            if (MODE == 2) {
                bf16x8 bu = *(const bf16x8*)(BsB + (wn * 32 + ln31) * 128 + ccb);
                bf16x8 bg = *(const bf16x8*)(BsB + (64 + wn * 32 + ln31) * 128 + ccb);
                acc[0][0] = __builtin_amdgcn_mfma_f32_32x32x16_bf16(a0, bu, acc[0][0], 0, 0, 0);
                acc[1][0] = __builtin_amdgcn_mfma_f32_32x32x16_bf16(a1, bu, acc[1][0], 0, 0, 0);
                accG[0] = __builtin_amdgcn_mfma_f32_32x32x16_bf16(a0, bg, accG[0], 0, 0, 0);
                accG[1] = __builtin_amdgcn_mfma_f32_32x32x16_bf16(a1, bg, accG[1], 0, 0, 0);
            } else {
#pragma unroll
                for (int nj = 0; nj < NF; ++nj) {
                    bf16x8 b = *(const bf16x8*)(BsB + (wn * WNC + nj * 32 + ln31) * 128 + ccb);
                    acc[0][nj] = __builtin_amdgcn_mfma_f32_32x32x16_bf16(a0, b, acc[0][nj], 0, 0, 0);
                    acc[1][nj] = __builtin_amdgcn_mfma_f32_32x32x16_bf16(a1, b, acc[1][nj], 0, 0, 0);
                }
            }
        }
        __syncthreads();
    }

    // ---- epilogue. C/D: col=lane&31, row=(reg&3)+8*(reg>>2)+4*(lane>>5)
    const float S2LOG = 0.17677669529663687f * 1.4426950408889634f;  // scale*log2e
    const int rbase = (int)m0 + wm * 64 + ((lane >> 5) << 2);
    const int cbase = n0 + wn * WNC + ln31;
#pragma unroll
    for (int mi = 0; mi < 2; ++mi) {
#pragma unroll
        for (int nj = 0; nj < NF; ++nj) {
            const int gc = cbase + nj * 32;
            const float bb = bias[gc];
            const float bgv = (MODE == 2) ? bias[768 + gc] : 0.f;
#pragma unroll
            for (int reg = 0; reg < 16; ++reg) {
                const int row = rbase + mi * 32 + (reg & 3) + ((reg >> 2) << 3);
                float v = acc[mi][nj][reg] + bb;
                if (MODE == 1) {
                    outF[(size_t)row * N + gc] += v;
                } else if (MODE == 0) {
                    int wnn = row / 343, qq = row - wnn * 343;
                    if (gc < 192) {          // Q * scale*log2e -> frag layout
                        int hh = gc >> 5, c = gc & 31;
                        int qt = qq >> 4, ql = qq & 15, gg = c >> 3, c8 = c & 7;
                        qT[(size_t)(wnn * NHEAD + hh) * 11264 + qt * 512 + gg * 128 + ql * 8 + c8] =
                            (_Float16)(v * S2LOG);
                    } else if (gc < 384) {   // K -> frag layout
                        int d = gc - 192, hh = d >> 5, c = d & 31;
                        int kt2 = qq >> 4, ql = qq & 15, gg = c >> 3, c8 = c & 7;
                        kT[(size_t)(wnn * NHEAD + hh) * 11264 + kt2 * 512 + gg * 128 + ql * 8 + c8] =
                            (_Float16)v;
                    } else {                 // V transposed
                        int d = gc - 384, hh = d >> 5, dd = d & 31;
                        outV[(((size_t)wnn * NHEAD + hh) * 32 + dd) * 344 + qq] = (_Float16)v;
                    }
                } else {
                    float g = accG[mi][reg] + bgv;
                    outB[(size_t)row * 768 + gc] = f2bf(v * gelu_tanh(g));
                }
            }
        }
    }
}

// ---------------- attn6: attn3 flow, but Q/K fragments read directly from global
// (wave-coalesced frag layout, L1/L2-resident). LDS = Vt + Pb = 47.6KB -> 3 blocks/CU.
__global__ __launch_bounds__(256) void k_attn6(const _Float16* __restrict__ qT,
                                               const _Float16* __restrict__ kT,
                                               const _Float16* __restrict__ vt,  // [128][6][32][344]
                                               const unsigned* __restrict__ cb,
                                               unsigned short* __restrict__ o) {
    __shared__ _Float16 Vt[32][360];       // 23040 B
    __shared__ _Float16 Pb[4][48][16][4];  // 24576 B, per-wave P buffer [k/4][q][4]
    const int h = blockIdx.x;
    const int wn = blockIdx.y;
    const int tid = threadIdx.x;
    const _Float16* vbase = vt + ((size_t)wn * NHEAD + h) * 32 * 344;
    for (int j = tid; j < 32 * 44; j += 256) {
        int d = j / 44, c = (j % 44) * 8;
        half8 v = {};
        if (c + 7 <= 342) {
            v = *(const half8*)&vbase[(size_t)d * 344 + c];
        } else if (c <= 342) {
#pragma unroll
            for (int i = 0; i < 8; ++i) v[i] = (c + i <= 342) ? vbase[(size_t)d * 344 + c + i] : (_Float16)0.f;
        }
        *(half8*)&Vt[d][c] = v;
    }
    __syncthreads();
    const int wid = tid >> 6, lane = tid & 63;
    const int qloc = lane & 15, g = lane >> 4;
    const _Float16* qb = qT + (size_t)(wn * NHEAD + h) * 11264;
    const _Float16* kb = kT + (size_t)(wn * NHEAD + h) * 11264;
    int cls = (((wn >> 5) == 3) ? 4 : 0) | ((((wn >> 2) & 7) == 7) ? 2 : 0) | (((wn & 3) == 3) ? 1 : 0);
    const unsigned* cbb = cb + (size_t)(cls * NHEAD + h) * 176 * 352;
    for (int qt = wid; qt < 22; qt += 4) {
        const int q0 = qt * 16;
        const int qrow = q0 + qloc;
        half8 qf = *(const half8*)&qb[qt * 512 + lane * 8];
        f32x4 st[22];
#pragma unroll
        for (int kt = 0; kt < 22; ++kt) {
            half8 kf = *(const half8*)&kb[kt * 512 + lane * 8];
            st[kt] = __builtin_amdgcn_mfma_f32_16x16x32_f16(kf, qf, (f32x4){0.f, 0.f, 0.f, 0.f}, 0, 0, 0);
        }
        float m = -1e30f;
#pragma unroll
        for (int kt = 0; kt < 22; ++kt) {
            const unsigned* cp = cbb + (size_t)(kt * 8 + g * 2) * 352 + q0 + qloc;
            unsigned b0 = cp[0];
            unsigned b1 = cp[352];
            __half2 h0 = *(__half2*)&b0, h1 = *(__half2*)&b1;
            st[kt][0] += __low2float(h0);
            st[kt][1] += __high2float(h0);
            st[kt][2] += __low2float(h1);
            st[kt][3] += __high2float(h1);
            m = fmaxf(m, fmaxf(fmaxf(st[kt][0], st[kt][1]), fmaxf(st[kt][2], st[kt][3])));
        }
        m = fmaxf(m, __shfl_xor(m, 16));
        m = fmaxf(m, __shfl_xor(m, 32));
        float l = 0.f;
        f32x4 acc0 = {0.f, 0.f, 0.f, 0.f}, acc1 = {0.f, 0.f, 0.f, 0.f};
        asm volatile("s_waitcnt lgkmcnt(0)" ::: "memory");
#pragma unroll
        for (int kt = 0; kt < 12; ++kt) {
            float p0 = exp2f(st[kt][0] - m), p1 = exp2f(st[kt][1] - m);
            float p2 = exp2f(st[kt][2] - m), p3 = exp2f(st[kt][3] - m);
            l += (p0 + p1) + (p2 + p3);
            half4 pv = {(_Float16)p0, (_Float16)p1, (_Float16)p2, (_Float16)p3};
            *(half4*)&Pb[wid][kt * 4 + g][qloc][0] = pv;
        }
        asm volatile("s_waitcnt lgkmcnt(0)" ::: "memory");
#pragma unroll
        for (int ks = 0; ks < 6; ++ks) {
            half4 pa = *(half4*)&Pb[wid][ks * 8 + g * 2][qloc][0];
            half4 pb = *(half4*)&Pb[wid][ks * 8 + g * 2 + 1][qloc][0];
            half8 pf = {pa[0], pa[1], pa[2], pa[3], pb[0], pb[1], pb[2], pb[3]};
            half8 v0 = *(const half8*)&Vt[qloc][ks * 32 + g * 8];
            half8 v1 = *(const half8*)&Vt[16 + qloc][ks * 32 + g * 8];
            acc0 = __builtin_amdgcn_mfma_f32_16x16x32_f16(v0, pf, acc0, 0, 0, 0);
            acc1 = __builtin_amdgcn_mfma_f32_16x16x32_f16(v1, pf, acc1, 0, 0, 0);
        }
        asm volatile("s_waitcnt lgkmcnt(0)" ::: "memory");
#pragma unroll
        for (int kt = 12; kt < 22; ++kt) {
            float p0 = exp2f(st[kt][0] - m), p1 = exp2f(st[kt][1] - m);
            float p2 = exp2f(st[kt][2] - m), p3 = exp2f(st[kt][3] - m);
            l += (p0 + p1) + (p2 + p3);
            half4 pv = {(_Float16)p0, (_Float16)p1, (_Float16)p2, (_Float16)p3};
            *(half4*)&Pb[wid][(kt - 12) * 4 + g][qloc][0] = pv;
        }
        asm volatile("s_waitcnt lgkmcnt(0)" ::: "memory");
#pragma unroll
        for (int ks = 0; ks < 5; ++ks) {
            half4 pa = *(half4*)&Pb[wid][ks * 8 + g * 2][qloc][0];
            half4 pb = *(half4*)&Pb[wid][ks * 8 + g * 2 + 1][qloc][0];
            half8 pf = {pa[0], pa[1], pa[2], pa[3], pb[0], pb[1], pb[2], pb[3]};
            half8 v0 = *(const half8*)&Vt[qloc][192 + ks * 32 + g * 8];
            half8 v1 = *(const half8*)&Vt[16 + qloc][192 + ks * 32 + g * 8];
            acc0 = __builtin_amdgcn_mfma_f32_16x16x32_f16(v0, pf, acc0, 0, 0, 0);
            acc1 = __builtin_amdgcn_mfma_f32_16x16x32_f16(v1, pf, acc1, 0, 0, 0);
        }
        l += __shfl_xor(l, 16);
        l += __shfl_xor(l, 32);
        if (qrow < SEQ) {
            float inv = 1.0f / l;
            unsigned short* orow = o + ((size_t)wn * SEQ + qrow) * CCH + h * 32;
            ushort2 w0 = {f2bf(acc0[0] * inv), f2bf(acc0[1] * inv)};
            ushort2 w1 = {f2bf(acc0[2] * inv), f2bf(acc0[3] * inv)};
            ushort2 w2 = {f2bf(acc1[0] * inv), f2bf(acc1[1] * inv)};
            ushort2 w3 = {f2bf(acc1[2] * inv), f2bf(acc1[3] * inv)};
            *(ushort2*)&orow[g * 4] = w0;
            *(ushort2*)&orow[g * 4 + 2] = w1;
            *(ushort2*)&orow[16 + g * 4] = w2;
            *(ushort2*)&orow[16 + g * 4 + 2] = w3;
        }
    }
}

extern "C" void kernel_launch(void* const* d_in, const int* in_sizes, int n_in,
                              void* d_out, int out_size, void* d_ws, size_t ws_size,
                              hipStream_t stream) {
    const float* x     = (const float*)d_in[0];
    const float* mask  = (const float*)d_in[1];
    const float* ln1_w = (const float*)d_in[3];
    const float* ln1_b = (const float*)d_in[4];
    const float* qkv_w = (const float*)d_in[5];
    const float* qkv_b = (const float*)d_in[6];
    const float* out_w = (const float*)d_in[7];
    const float* out_b = (const float*)d_in[8];
    const float* ln2_w = (const float*)d_in[9];
    const float* ln2_b = (const float*)d_in[10];
    const float* ff1_w = (const float*)d_in[11];
    const float* ff1_b = (const float*)d_in[12];
    const float* ff2_w = (const float*)d_in[13];
    const float* ff2_b = (const float*)d_in[14];
    const float* rpb   = (const float*)d_in[15];
    const float* lnf_w = (const float*)d_in[16];
    const float* lnf_b = (const float*)d_in[17];

    char* wsp = (char*)d_ws;
    float* xw = (float*)wsp;                          wsp += (size_t)TOK * 192 * 4;
    unsigned short* hdnb = (unsigned short*)wsp;      wsp += (size_t)TOK * 192 * 2;
    _Float16* qTh = (_Float16*)wsp;                   wsp += (size_t)768 * 11264 * 2;
    _Float16* kTh = (_Float16*)wsp;                   wsp += (size_t)768 * 11264 * 2;
    _Float16* vth = (_Float16*)wsp;                   wsp += (size_t)NWIN * NHEAD * 32 * 344 * 2;
    unsigned short* glub = (unsigned short*)wsp;      wsp += (size_t)TOK * 768 * 2;
    unsigned short* wt = (unsigned short*)wsp;        wsp += (size_t)1179648 * 2;
    unsigned* cb = (unsigned*)wsp;                    // 48*176*352*4 = 11.9 MB
    float* out = (float*)d_out;

    k_shift_part<<<8232, 256, 0, stream>>>(x, xw);
    k_wprep<<<4608, 256, 0, stream>>>(qkv_w, out_w, ff1_w, ff2_w, wt);
    k_zfill<<<768, 288, 0, stream>>>(qTh, kTh);
    for (int l = 0; l < 2; ++l) {
        unsigned short* wbase = wt + (size_t)l * 589824;
        k_cbgen2<<<dim3(176, NHEAD, 8), 352, 0, stream>>>(mask, rpb + (size_t)l * 2197 * NHEAD, cb);
        k_ln_bf<<<10976, 256, 0, stream>>>(xw, ln1_w + l * 192, ln1_b + l * 192, hdnb, TOK);
        k_gemm32<0><<<dim3(3, 343), 256, 0, stream>>>(hdnb, wbase, qkv_b + l * 576,
                                                      nullptr, nullptr, qTh, kTh, vth, 576, 192);
        k_attn6<<<dim3(NHEAD, NWIN), 256, 0, stream>>>(qTh, kTh, vth, cb, hdnb);
        k_gemm32<1><<<dim3(3, 343), 256, 0, stream>>>(hdnb, wbase + 110592, out_b + l * 192,
                                                      xw, nullptr, nullptr, nullptr, nullptr, 192, 192);
        k_ln_bf<<<10976, 256, 0, stream>>>(xw, ln2_w + l * 192, ln2_b + l * 192, hdnb, TOK);
        k_gemm32<2><<<dim3(12, 343), 256, 0, stream>>>(hdnb, wbase + 147456, ff1_b + l * 1536,
                                                       nullptr, glub, nullptr, nullptr, nullptr, 768, 192);
        k_gemm32<1><<<dim3(3, 343), 256, 0, stream>>>(glub, wbase + 442368, ff2_b + l * 192,
                                                      xw, nullptr, nullptr, nullptr, nullptr, 192, 768);
    }
    k_ln_out<<<10976, 256, 0, stream>>>(xw, lnf_w, lnf_b, out);
}

// Round 11
// 578.409 us; speedup vs baseline: 1.6069x; 1.1669x over previous
//
#include <hip/hip_runtime.h>
#include <hip/hip_fp16.h>
#include <math.h>

#define SEQ 343
#define CCH 192
#define NWIN 128
#define NHEAD 6
#define TOK (NWIN * SEQ)  // 43904

typedef __bf16 bf16x8 __attribute__((ext_vector_type(8)));
typedef float f32x4 __attribute__((ext_vector_type(4)));
typedef float f32x16 __attribute__((ext_vector_type(16)));
typedef unsigned short ushort8 __attribute__((ext_vector_type(8)));
typedef _Float16 half8 __attribute__((ext_vector_type(8)));
typedef _Float16 half4 __attribute__((ext_vector_type(4)));

__device__ __forceinline__ unsigned short f2bf(float f) {
    unsigned u = __float_as_uint(f);
    u += 0x7FFF + ((u >> 16) & 1);
    return (unsigned short)(u >> 16);
}

// tanh-approx gelu (matches jax.nn.gelu approximate=True), via fast exp
__device__ __forceinline__ float gelu_tanh(float x) {
    const float k0 = 0.7978845608028654f;
    const float k1 = 0.044715f;
    float y = k0 * (x + k1 * x * x * x);
    float t = 1.0f - 2.0f / (__expf(2.0f * y) + 1.0f);
    return 0.5f * x * (1.0f + t);
}

// async global->LDS, 16B per lane
__device__ __forceinline__ void gld16(void* l, const void* g) {
    __builtin_amdgcn_global_load_lds((const __attribute__((address_space(1))) unsigned int*)g,
                                     (__attribute__((address_space(3))) unsigned int*)l, 16, 0, 0);
}

// ---------------- shift (+3 src) + window partition: x(28,56,28,192) -> xw(128,343,192) fp32
__global__ __launch_bounds__(256) void k_shift_part(const float* __restrict__ x,
                                                    float* __restrict__ xw) {
    int idx = blockIdx.x * 256 + threadIdx.x;  // float4 index
    if (idx >= TOK * 48) return;
    int c4 = idx % 48;
    int tok = idx / 48;
    int t = tok % SEQ;
    int wn = tok / SEQ;
    int tw = t % 7, th = (t / 7) % 7, td = t / 49;
    int ww = wn & 3, wh = (wn >> 2) & 7, wd = wn >> 5;
    int sd = (wd * 7 + td + 3) % 28;
    int sh = (wh * 7 + th + 3) % 56;
    int sw = (ww * 7 + tw + 3) % 28;
    const float4* src = (const float4*)(x + (size_t)((sd * 56 + sh) * 28 + sw) * CCH);
    ((float4*)xw)[idx] = src[c4];
}

// ---------------- LayerNorm fp32 -> bf16 (GEMM A operand)
__global__ __launch_bounds__(256) void k_ln_bf(const float* __restrict__ in,
                                               const float* __restrict__ w,
                                               const float* __restrict__ b,
                                               unsigned short* __restrict__ out, int rows) {
    int row = blockIdx.x * 4 + (threadIdx.x >> 6);
    int lane = threadIdx.x & 63;
    if (row >= rows) return;
    const float* p = in + (size_t)row * CCH;
    float v0 = p[lane], v1 = p[lane + 64], v2 = p[lane + 128];
    float s = v0 + v1 + v2;
#pragma unroll
    for (int off = 32; off > 0; off >>= 1) s += __shfl_xor(s, off);
    float mu = s * (1.0f / 192.0f);
    float d0 = v0 - mu, d1 = v1 - mu, d2 = v2 - mu;
    float vv = d0 * d0 + d1 * d1 + d2 * d2;
#pragma unroll
    for (int off = 32; off > 0; off >>= 1) vv += __shfl_xor(vv, off);
    float rs = rsqrtf(vv * (1.0f / 192.0f) + 1e-5f);
    unsigned short* q = out + (size_t)row * CCH;
    q[lane] = f2bf(d0 * rs * w[lane] + b[lane]);
    q[lane + 64] = f2bf(d1 * rs * w[lane + 64] + b[lane + 64]);
    q[lane + 128] = f2bf(d2 * rs * w[lane + 128] + b[lane + 128]);
}

// ---------------- final LN + window reverse + roll(+3) -> d_out (fp32)
__global__ __launch_bounds__(256) void k_ln_out(const float* __restrict__ xw,
                                                const float* __restrict__ w,
                                                const float* __restrict__ b,
                                                float* __restrict__ out) {
    int row = blockIdx.x * 4 + (threadIdx.x >> 6);
    int lane = threadIdx.x & 63;
    if (row >= TOK) return;
    int d = row / 1568;
    int hh = (row / 28) % 56;
    int wv = row % 28;
    int sd = (d + 25) % 28, sh = (hh + 53) % 56, sw = (wv + 25) % 28;
    int wn = (sd / 7) * 32 + (sh / 7) * 4 + (sw / 7);
    int t = (sd % 7) * 49 + (sh % 7) * 7 + (sw % 7);
    const float* p = xw + ((size_t)wn * SEQ + t) * CCH;
    float v0 = p[lane], v1 = p[lane + 64], v2 = p[lane + 128];
    float s = v0 + v1 + v2;
#pragma unroll
    for (int off = 32; off > 0; off >>= 1) s += __shfl_xor(s, off);
    float mu = s * (1.0f / 192.0f);
    float d0 = v0 - mu, d1 = v1 - mu, d2 = v2 - mu;
    float vv = d0 * d0 + d1 * d1 + d2 * d2;
#pragma unroll
    for (int off = 32; off > 0; off >>= 1) vv += __shfl_xor(vv, off);
    float rs = rsqrtf(vv * (1.0f / 192.0f) + 1e-5f);
    float* q = out + (size_t)row * CCH;
    q[lane] = d0 * rs * w[lane] + b[lane];
    q[lane + 64] = d1 * rs * w[lane + 64] + b[lane + 64];
    q[lane + 128] = d2 * rs * w[lane + 128] + b[lane + 128];
}

// ---------------- weight prep: fp32 [K][N] -> bf16 transposed [N][K], both layers
__global__ __launch_bounds__(256) void k_wprep(const float* __restrict__ qkv_w,
                                               const float* __restrict__ out_w,
                                               const float* __restrict__ ff1_w,
                                               const float* __restrict__ ff2_w,
                                               unsigned short* __restrict__ wt) {
    int idx = blockIdx.x * 256 + threadIdx.x;
    if (idx >= 1179648) return;
    int l = idx / 589824;
    int r = idx - l * 589824;
    const float* src;
    int Kd, Nd, off;
    if (r < 110592)      { src = qkv_w + (size_t)l * 110592; Kd = 192; Nd = 576;  off = r; }
    else if (r < 147456) { src = out_w + (size_t)l * 36864;  Kd = 192; Nd = 192;  off = r - 110592; }
    else if (r < 442368) { src = ff1_w + (size_t)l * 294912; Kd = 192; Nd = 1536; off = r - 147456; }
    else                 { src = ff2_w + (size_t)l * 147456; Kd = 768; Nd = 192;  off = r - 442368; }
    int n = off / Kd, k = off - n * Kd;
    wt[idx] = f2bf(src[(size_t)k * Nd + n]);
}

// ---------------- combined mask+bias (log2 domain): cb[cl][h][kp][q], f16 pair for k=2kp,2kp+1
__global__ void k_cbgen2(const float* __restrict__ mask, const float* __restrict__ rpb,
                         unsigned* __restrict__ cb) {
    int q = threadIdx.x;   // 0..351
    int kp = blockIdx.x;   // 0..175
    int h = blockIdx.y;    // 0..5
    int cl = blockIdx.z;   // 0..7
    int wn = ((cl & 4) ? 96 : 0) + ((cl & 2) ? 28 : 0) + ((cl & 1) ? 3 : 0);
    const float LOG2E = 1.4426950408889634f;
    int qd = q / 49, qh = (q / 7) % 7, qw = q % 7;
    unsigned short v[2];
#pragma unroll
    for (int t = 0; t < 2; ++t) {
        int k = 2 * kp + t;
        float val = -14000.0f;
        if (k < SEQ && q < SEQ) {
            float mk = mask[((size_t)wn * SEQ + k) * SEQ + q];  // mask symmetric in !=0
            if (mk == 0.0f) {
                int kd = k / 49, kh = (k / 7) % 7, kw = k % 7;
                int rel = (qd - kd + 6) * 169 + (qh - kh + 6) * 13 + (qw - kw + 6);
                val = rpb[(size_t)rel * NHEAD + h] * LOG2E;
            }
        }
        v[t] = __half_as_ushort(__float2half_rn(val));
    }
    cb[((size_t)(cl * NHEAD + h) * 176 + kp) * 352 + q] = (unsigned)v[0] | ((unsigned)v[1] << 16);
}

// ---------------- 32x32x16 MFMA GEMM (round-4 proven structure), global_load_lds staging,
// XOR-swizzle (pre-swizzled global source, linear LDS). BM=128, BK=64.
// MODE 0 (qkv): BN=192 -> Q(scaled)/K -> outH[row][384]; V -> outV transposed.
// MODE 1: BN=64, outF += acc + bias (residual fp32)
// MODE 2 (GLU): BN=64, Wt rows [n0,n0+64)=u, [768+n0,...)=g; outB = bf16(u * gelu(g))
template <int MODE>
__global__ __launch_bounds__(256) void k_gemm32(const unsigned short* __restrict__ A,
                                                const unsigned short* __restrict__ Wt,
                                                const float* __restrict__ bias,
                                                float* __restrict__ outF,
                                                unsigned short* __restrict__ outB,
                                                _Float16* __restrict__ outH,
                                                _Float16* __restrict__ outV,
                                                int N, int K) {
    constexpr int BN = (MODE == 0) ? 192 : 64;
    constexpr int NF = (MODE == 0) ? 3 : 1;          // n-frags (of 32) per wave
    constexpr int WNC = NF * 32;                     // wave n-extent
    constexpr int BROWS = (MODE == 0) ? 192 : ((MODE == 2) ? 128 : 64);
    constexpr int BCH = (BROWS * 128) / 4096;        // B DMA chunks
    __shared__ char AsB[16384];
    __shared__ char BsB[BROWS * 128];
    const int tid = threadIdx.x;
    const int n0 = blockIdx.x * BN;
    const size_t m0 = (size_t)blockIdx.y * 128;
    const int lane = tid & 63, wid = tid >> 6;
    const int wm = wid >> 1, wn = wid & 1;
    const int ln31 = lane & 31, hi16 = (lane >> 5) * 16;
    const int xorv = (ln31 & 7) << 4;
    const size_t ldb = (size_t)K * 2;  // row pitch (bytes) of both A and Wt

    f32x16 acc[2][NF];
    f32x16 accG[2];
#pragma unroll
    for (int mi = 0; mi < 2; ++mi) {
#pragma unroll
        for (int nj = 0; nj < NF; ++nj) acc[mi][nj] = (f32x16)(0.f);
        accG[mi] = (f32x16)(0.f);
    }

    for (int kb = 0; kb < K; kb += 64) {
        // ---- stage A (16 KB) + B via DMA, global source pre-swizzled
#pragma unroll
        for (int i = 0; i < 4; ++i) {
            int s = i * 4096 + tid * 16;
            int r = s >> 7;
            int cbx = (s & 127) ^ ((r & 7) << 4);
            gld16(AsB + s, (const char*)A + (m0 + r) * ldb + (size_t)kb * 2 + cbx);
        }
#pragma unroll
        for (int i = 0; i < BCH; ++i) {
            int s = i * 4096 + tid * 16;
            int r = s >> 7;
            int cbx = (s & 127) ^ ((r & 7) << 4);
            int grow = n0 + r + ((MODE == 2 && r >= 64) ? 704 : 0);
            gld16(BsB + s, (const char*)Wt + (size_t)grow * ldb + (size_t)kb * 2 + cbx);
        }
        __syncthreads();
        // ---- compute 4 k-steps of 16
#pragma unroll
        for (int ks = 0; ks < 4; ++ks) {
            const int ccb = (ks * 32 + hi16) ^ xorv;
            bf16x8 a0 = *(const bf16x8*)(AsB + (wm * 64 + ln31) * 128 + ccb);
            bf16x8 a1 = *(const bf16x8*)(AsB + (wm * 64 + 32 + ln31) * 128 + ccb);
            if (MODE == 2) {
                bf16x8 bu = *(const bf16x8*)(BsB + (wn * 32 + ln31) * 128 + ccb);
                bf16x8 bg = *(const bf16x8*)(BsB + (64 + wn * 32 + ln31) * 128 + ccb);
                acc[0][0] = __builtin_amdgcn_mfma_f32_32x32x16_bf16(a0, bu, acc[0][0], 0, 0, 0);
                acc[1][0] = __builtin_amdgcn_mfma_f32_32x32x16_bf16(a1, bu, acc[1][0], 0, 0, 0);
                accG[0] = __builtin_amdgcn_mfma_f32_32x32x16_bf16(a0, bg, accG[0], 0, 0, 0);
                accG[1] = __builtin_amdgcn_mfma_f32_32x32x16_bf16(a1, bg, accG[1], 0, 0, 0);
            } else {
#pragma unroll
                for (int nj = 0; nj < NF; ++nj) {
                    bf16x8 b = *(const bf16x8*)(BsB + (wn * WNC + nj * 32 + ln31) * 128 + ccb);
                    acc[0][nj] = __builtin_amdgcn_mfma_f32_32x32x16_bf16(a0, b, acc[0][nj], 0, 0, 0);
                    acc[1][nj] = __builtin_amdgcn_mfma_f32_32x32x16_bf16(a1, b, acc[1][nj], 0, 0, 0);
                }
            }
        }
        __syncthreads();
    }

    // ---- epilogue. C/D: col=lane&31, row=(reg&3)+8*(reg>>2)+4*(lane>>5)
    const float S2LOG = 0.17677669529663687f * 1.4426950408889634f;  // scale*log2e
    const int rbase = (int)m0 + wm * 64 + ((lane >> 5) << 2);
    const int cbase = n0 + wn * WNC + ln31;
#pragma unroll
    for (int mi = 0; mi < 2; ++mi) {
#pragma unroll
        for (int nj = 0; nj < NF; ++nj) {
            const int gc = cbase + nj * 32;
            const float bb = bias[gc];
            const float bgv = (MODE == 2) ? bias[768 + gc] : 0.f;
#pragma unroll
            for (int reg = 0; reg < 16; ++reg) {
                const int row = rbase + mi * 32 + (reg & 3) + ((reg >> 2) << 3);
                float v = acc[mi][nj][reg] + bb;
                if (MODE == 1) {
                    outF[(size_t)row * N + gc] += v;
                } else if (MODE == 0) {
                    if (gc < 384) {
                        outH[(size_t)row * 384 + gc] = (_Float16)(gc < 192 ? v * S2LOG : v);
                    } else {
                        int d = gc - 384, hh = d >> 5, dd = d & 31;
                        int wnn = row / 343, qq = row - wnn * 343;
                        outV[(((size_t)wnn * NHEAD + hh) * 32 + dd) * 344 + qq] = (_Float16)v;
                    }
                } else {
                    float g = accG[mi][reg] + bgv;
                    outB[(size_t)row * 768 + gc] = f2bf(v * gelu_tanh(g));
                }
            }
        }
    }
}

// ---------------- attn7: attn3 compute flow; LDS cut to 53.0KB (3 blocks/CU, one round):
// Ks/Vt chunk-XOR swizzle (slot = c ^ (row&3)), Pb shrunk to 8KB via 6 P-passes.
__global__ __launch_bounds__(256) void k_attn7(const _Float16* __restrict__ qk,  // [TOK][384]
                                               const _Float16* __restrict__ vt,  // [128][6][32][344]
                                               const unsigned* __restrict__ cb,
                                               unsigned short* __restrict__ o) {
    __shared__ _Float16 Ks[352 * 32];      // 22528 B, slot = c ^ (s&3)
    __shared__ _Float16 Vt[32 * 352];      // 22528 B, slot = c ^ (d&3)
    __shared__ _Float16 Pb[4][16][16][4];  // 8192 B, per-wave P buffer (1 pass = <=16 rows)
    const int h = blockIdx.x;
    const int wn = blockIdx.y;
    const int tid = threadIdx.x;
    // stage K (rows >= 343 zero-filled)
    const _Float16* kbase = qk + (size_t)wn * SEQ * 384 + 192 + h * 32;
    for (int j = tid; j < 1408; j += 256) {
        int s = j >> 2, c = j & 3;
        half8 v = {};
        if (s < SEQ) v = *(const half8*)&kbase[(size_t)s * 384 + c * 8];
        *(half8*)&Ks[s * 32 + (c ^ (s & 3)) * 8] = v;
    }
    // stage V^T (k >= 343 zero-filled)
    const _Float16* vbase = vt + ((size_t)wn * NHEAD + h) * 32 * 344;
    for (int j = tid; j < 1408; j += 256) {
        int d = j / 44, c = j % 44;
        int c8 = c * 8;
        half8 v = {};
        if (c8 + 7 <= 342) {
            v = *(const half8*)&vbase[(size_t)d * 344 + c8];
        } else if (c8 <= 342) {
#pragma unroll
            for (int i = 0; i < 8; ++i) v[i] = (c8 + i <= 342) ? vbase[(size_t)d * 344 + c8 + i] : (_Float16)0.f;
        }
        *(half8*)&Vt[d * 352 + (c ^ (d & 3)) * 8] = v;
    }
    __syncthreads();
    const int wid = tid >> 6, lane = tid & 63;
    const int qloc = lane & 15, g = lane >> 4;
    const int x3 = qloc & 3;
    const int gk = (g ^ x3) * 8;   // Ks chunk slot offset
    int cls = (((wn >> 5) == 3) ? 4 : 0) | ((((wn >> 2) & 7) == 7) ? 2 : 0) | (((wn & 3) == 3) ? 1 : 0);
    const unsigned* cbb = cb + (size_t)(cls * NHEAD + h) * 176 * 352;
    for (int qt = wid; qt < 22; qt += 4) {
        const int q0 = qt * 16;
        const int qrow = q0 + qloc;
        half8 qf = {};
        if (qrow < SEQ) qf = *(const half8*)&qk[((size_t)wn * SEQ + qrow) * 384 + h * 32 + g * 8];
        f32x4 st[22];
#pragma unroll
        for (int kt = 0; kt < 22; ++kt) {
            half8 kf = *(const half8*)&Ks[(kt * 16 + qloc) * 32 + gk];
            st[kt] = __builtin_amdgcn_mfma_f32_16x16x32_f16(kf, qf, (f32x4){0.f, 0.f, 0.f, 0.f}, 0, 0, 0);
        }
        float m = -1e30f;
#pragma unroll
        for (int kt = 0; kt < 22; ++kt) {
            const unsigned* cp = cbb + (size_t)(kt * 8 + g * 2) * 352 + q0 + qloc;
            unsigned b0 = cp[0];
            unsigned b1 = cp[352];
            __half2 h0 = *(__half2*)&b0, h1 = *(__half2*)&b1;
            st[kt][0] += __low2float(h0);
            st[kt][1] += __high2float(h0);
            st[kt][2] += __low2float(h1);
            st[kt][3] += __high2float(h1);
            m = fmaxf(m, fmaxf(fmaxf(st[kt][0], st[kt][1]), fmaxf(st[kt][2], st[kt][3])));
        }
        m = fmaxf(m, __shfl_xor(m, 16));
        m = fmaxf(m, __shfl_xor(m, 32));
        float l = 0.f;
        f32x4 acc0 = {0.f, 0.f, 0.f, 0.f}, acc1 = {0.f, 0.f, 0.f, 0.f};
        // 6 passes: 5 x (write 4 kt -> read 2 PV steps) + 1 x (write 2 kt -> 1 PV step)
#pragma unroll
        for (int pass = 0; pass < 6; ++pass) {
            const int nkt = (pass < 5) ? 4 : 2;
            asm volatile("s_waitcnt lgkmcnt(0)" ::: "memory");  // prior Pb reads done
#pragma unroll
            for (int t = 0; t < nkt; ++t) {
                int kt = pass * 4 + t;
                float p0 = exp2f(st[kt][0] - m), p1 = exp2f(st[kt][1] - m);
                float p2 = exp2f(st[kt][2] - m), p3 = exp2f(st[kt][3] - m);
                l += (p0 + p1) + (p2 + p3);
                half4 pv = {(_Float16)p0, (_Float16)p1, (_Float16)p2, (_Float16)p3};
                *(half4*)&Pb[wid][t * 4 + g][qloc][0] = pv;
            }
            asm volatile("s_waitcnt lgkmcnt(0)" ::: "memory");  // writes visible
#pragma unroll
            for (int ps = 0; ps < nkt / 2; ++ps) {
                half4 pa = *(half4*)&Pb[wid][ps * 8 + g * 2][qloc][0];
                half4 pb = *(half4*)&Pb[wid][ps * 8 + g * 2 + 1][qloc][0];
                half8 pf = {pa[0], pa[1], pa[2], pa[3], pb[0], pb[1], pb[2], pb[3]};
                const int slotV = (pass * 8 + ps * 4 + (g ^ x3)) * 8;
                half8 v0 = *(const half8*)&Vt[qloc * 352 + slotV];
                half8 v1 = *(const half8*)&Vt[(qloc + 16) * 352 + slotV];
                acc0 = __builtin_amdgcn_mfma_f32_16x16x32_f16(v0, pf, acc0, 0, 0, 0);
                acc1 = __builtin_amdgcn_mfma_f32_16x16x32_f16(v1, pf, acc1, 0, 0, 0);
            }
        }
        l += __shfl_xor(l, 16);
        l += __shfl_xor(l, 32);
        if (qrow < SEQ) {
            float inv = 1.0f / l;
            unsigned short* orow = o + ((size_t)wn * SEQ + qrow) * CCH + h * 32;
            ushort2 w0 = {f2bf(acc0[0] * inv), f2bf(acc0[1] * inv)};
            ushort2 w1 = {f2bf(acc0[2] * inv), f2bf(acc0[3] * inv)};
            ushort2 w2 = {f2bf(acc1[0] * inv), f2bf(acc1[1] * inv)};
            ushort2 w3 = {f2bf(acc1[2] * inv), f2bf(acc1[3] * inv)};
            *(ushort2*)&orow[g * 4] = w0;
            *(ushort2*)&orow[g * 4 + 2] = w1;
            *(ushort2*)&orow[16 + g * 4] = w2;
            *(ushort2*)&orow[16 + g * 4 + 2] = w3;
        }
    }
}

extern "C" void kernel_launch(void* const* d_in, const int* in_sizes, int n_in,
                              void* d_out, int out_size, void* d_ws, size_t ws_size,
                              hipStream_t stream) {
    const float* x     = (const float*)d_in[0];
    const float* mask  = (const float*)d_in[1];
    const float* ln1_w = (const float*)d_in[3];
    const float* ln1_b = (const float*)d_in[4];
    const float* qkv_w = (const float*)d_in[5];
    const float* qkv_b = (const float*)d_in[6];
    const float* out_w = (const float*)d_in[7];
    const float* out_b = (const float*)d_in[8];
    const float* ln2_w = (const float*)d_in[9];
    const float* ln2_b = (const float*)d_in[10];
    const float* ff1_w = (const float*)d_in[11];
    const float* ff1_b = (const float*)d_in[12];
    const float* ff2_w = (const float*)d_in[13];
    const float* ff2_b = (const float*)d_in[14];
    const float* rpb   = (const float*)d_in[15];
    const float* lnf_w = (const float*)d_in[16];
    const float* lnf_b = (const float*)d_in[17];

    char* wsp = (char*)d_ws;
    float* xw = (float*)wsp;                          wsp += (size_t)TOK * 192 * 4;
    unsigned short* hdnb = (unsigned short*)wsp;      wsp += (size_t)TOK * 192 * 2;
    _Float16* qkh = (_Float16*)wsp;                   wsp += (size_t)TOK * 384 * 2;
    _Float16* vth = (_Float16*)wsp;                   wsp += (size_t)NWIN * NHEAD * 32 * 344 * 2;
    unsigned short* glub = (unsigned short*)wsp;      wsp += (size_t)TOK * 768 * 2;
    unsigned short* wt = (unsigned short*)wsp;        wsp += (size_t)1179648 * 2;
    unsigned* cb = (unsigned*)wsp;                    // 48*176*352*4 = 11.9 MB
    float* out = (float*)d_out;

    k_shift_part<<<8232, 256, 0, stream>>>(x, xw);
    k_wprep<<<4608, 256, 0, stream>>>(qkv_w, out_w, ff1_w, ff2_w, wt);
    for (int l = 0; l < 2; ++l) {
        unsigned short* wbase = wt + (size_t)l * 589824;
        k_cbgen2<<<dim3(176, NHEAD, 8), 352, 0, stream>>>(mask, rpb + (size_t)l * 2197 * NHEAD, cb);
        k_ln_bf<<<10976, 256, 0, stream>>>(xw, ln1_w + l * 192, ln1_b + l * 192, hdnb, TOK);
        k_gemm32<0><<<dim3(3, 343), 256, 0, stream>>>(hdnb, wbase, qkv_b + l * 576,
                                                      nullptr, nullptr, qkh, vth, 576, 192);
        k_attn7<<<dim3(NHEAD, NWIN), 256, 0, stream>>>(qkh, vth, cb, hdnb);
        k_gemm32<1><<<dim3(3, 343), 256, 0, stream>>>(hdnb, wbase + 110592, out_b + l * 192,
                                                      xw, nullptr, nullptr, nullptr, 192, 192);
        k_ln_bf<<<10976, 256, 0, stream>>>(xw, ln2_w + l * 192, ln2_b + l * 192, hdnb, TOK);
        k_gemm32<2><<<dim3(12, 343), 256, 0, stream>>>(hdnb, wbase + 147456, ff1_b + l * 1536,
                                                       nullptr, glub, nullptr, nullptr, 768, 192);
        k_gemm32<1><<<dim3(3, 343), 256, 0, stream>>>(glub, wbase + 442368, ff2_b + l * 192,
                                                      xw, nullptr, nullptr, nullptr, 192, 768);
    }
    k_ln_out<<<10976, 256, 0, stream>>>(xw, lnf_w, lnf_b, out);
}